// Round 11
// baseline (140.157 us; speedup 1.0000x reference)
//
#include <hip/hip_runtime.h>

// SAGEConv: h[50000,64] f32, src/dst[800000] int32, W[128,64] f32, b[64] f32
// out = concat(h, mean_{in-edges}(h[src])) @ W + b
//
// R11: 2 GPU ops (prep, fused). Kills prep's scattered bucket writes
// (R9 accounting: prep ~74us from ~51MB effective RMW line traffic, same
// pathology as R4's fill):
//  - prep: per-4096-edge-tile counting sort in LDS (count w/ rank capture,
//    1024-wide ping-pong scan, LDS scatter), then CONTIGUOUS coalesced
//    uint4 tile write + ushort offs[tile][k] table. All writes coalesced.
//  - fused: phase A' gathers the bucket's 196 tile-segments (reads, no RMW)
//    into LDS list_raw (aliases hn; dead ranges don't overlap), then R9's
//    single-atomic-pass CSR + 16-lane ushort4 gather + MLP unchanged.
//    (R10's 8-lane gather regressed 50->66us: reverted.)
// Lessons: read-side reduction only (R6); scattered 4B global writes cost
// 64B RMW lines (R4/R9) -> sort locally, write contiguously.

#define IN_FEAT 64
#define KB_SHIFT 6            // 64 nodes per bucket
#define BKN 64
#define CAP 2048              // max pairs per bucket (mean 1024, +32 sigma)
#define KPAD 1024             // scan width >= K+1 (K=782)
#define STILE 4096            // edges per sort tile

__device__ __forceinline__ unsigned short f2bf(float f) {
    unsigned u = __float_as_uint(f);
    return (unsigned short)((u + 0x7FFFu + ((u >> 16) & 1u)) >> 16);
}
__device__ __forceinline__ float bf2f(unsigned short s) {
    return __uint_as_float(((unsigned)s) << 16);
}

// ---- k1: blocks [0,conv_tiles): h->bf16 ; rest: tile counting sort ---------
__global__ __launch_bounds__(512) void sage_prep(
    const float* __restrict__ h, const int* __restrict__ src,
    const int* __restrict__ dst,
    unsigned short* __restrict__ hb, unsigned* __restrict__ pairs,
    unsigned short* __restrict__ offs,   // [n_stiles][K+1]
    int n4, int n_edges, int conv_tiles, int K)
{
    __shared__ int cnt[KPAD];            // 4 KB
    __shared__ int sA[KPAD];             // 4 KB
    __shared__ int sB[KPAD];             // 4 KB
    __shared__ unsigned stage[STILE];    // 16 KB
    int t = (int)threadIdx.x;

    if ((int)blockIdx.x < conv_tiles) {
        int tb = blockIdx.x * 8192;
        #pragma unroll
        for (int i = 0; i < 16; ++i) {
            int idx = tb + t + i * 512;            // float4 index
            if (idx < n4) {
                float4 v = ((const float4*)h)[idx];
                ushort4 r;
                r.x = f2bf(v.x); r.y = f2bf(v.y);
                r.z = f2bf(v.z); r.w = f2bf(v.w);
                ((ushort4*)hb)[idx] = r;
            }
        }
        return;
    }

    const int tile  = (int)blockIdx.x - conv_tiles;
    const int ebase = tile * STILE;
    const int m_t   = min(STILE, n_edges - ebase);

    for (int k = t; k < KPAD; k += 512) cnt[k] = 0;
    __syncthreads();

    // count with rank capture
    int kb[8]; unsigned pk[8]; int rk[8];
    #pragma unroll
    for (int i = 0; i < 8; ++i) {
        int e = ebase + t + i * 512;
        kb[i] = -1;
        if (e < n_edges) {
            int d = dst[e], s = src[e];
            kb[i] = d >> KB_SHIFT;
            pk[i] = ((unsigned)s << KB_SHIFT) | (unsigned)(d & (BKN - 1));
            rk[i] = atomicAdd(&cnt[kb[i]], 1);
        }
    }
    __syncthreads();

    // inclusive scan over KPAD counters (ping-pong, 2 elems/thread)
    for (int k = t; k < KPAD; k += 512) sA[k] = cnt[k];
    __syncthreads();
    int* sc = sA; int* sd = sB;
    for (int off = 1; off < KPAD; off <<= 1) {
        for (int k = t; k < KPAD; k += 512)
            sd[k] = sc[k] + ((k >= off) ? sc[k - off] : 0);
        __syncthreads();
        int* tmp = sc; sc = sd; sd = tmp;
    }
    // sc = inclusive; exclusive = sc[k] - cnt[k]

    // LDS scatter into sorted order
    #pragma unroll
    for (int i = 0; i < 8; ++i)
        if (kb[i] >= 0)
            stage[sc[kb[i]] - cnt[kb[i]] + rk[i]] = pk[i];
    // per-tile offsets (ushort; values <= 4096)
    for (int k = t; k <= K; k += 512)
        offs[(size_t)tile * (K + 1) + k] =
            (unsigned short)((k < K) ? (sc[k] - cnt[k]) : m_t);
    __syncthreads();

    // contiguous coalesced write of the sorted tile
    uint4* pd = (uint4*)(pairs + (size_t)tile * STILE);
    const uint4* ps = (const uint4*)stage;
    pd[t]       = ps[t];
    pd[t + 512] = ps[t + 512];
}

// ---- k2: segment-gather + local CSR + gather-mean + MLP --------------------
// One block (512 thr, 8 waves) per 64-node bucket. LDS ~52KB -> 3 blk/CU.
//  A': pull the bucket's per-tile segments (reads only) into list_raw
//      (aliases hn's LDS; list_raw dead before hn is first written).
//  A : R9 single-atomic-pass CSR (count w/ rank capture, wave-0 scan).
//  B : wave w gathers nodes w*8..w*8+7: 16 lanes/edge x ushort4, 4-deep
//      unroll, __shfl_xor(16,32) reduce, mean -> bf16 hn.
//  C : MLP: wave w, pass p: node w*8+p*4+sub, cols 4q..4q+3.
__global__ __launch_bounds__(512, 6) void sage_fused(
    const unsigned short* __restrict__ hb,
    const float* __restrict__ h,
    const unsigned* __restrict__ pairs,
    const unsigned short* __restrict__ offs,
    const float* __restrict__ W,     // [128,64] row-major
    const float* __restrict__ bias,
    float* __restrict__ out,
    int n_nodes, int K, int n_stiles)
{
    __shared__ float Wsh[128][64];        // 32 KB
    __shared__ float bsh[64];
    __shared__ unsigned short hn[BKN][80];// 10.25 KB (bf16 means) | list_raw
    __shared__ int   list[CAP];           // 8 KB
    __shared__ int   cnt[BKN];
    __shared__ int   rs[BKN + 1];
    __shared__ int   mtot;

    unsigned* list_raw = (unsigned*)&hn[0][0];   // 2560 uints >= CAP

    const int t = (int)threadIdx.x;
    {   // stage W: 2048 float4s, 4 per thread
        float4* wd = (float4*)&Wsh[0][0];
        const float4* wsv = (const float4*)W;
        wd[t]        = wsv[t];
        wd[t + 512]  = wsv[t + 512];
        wd[t + 1024] = wsv[t + 1024];
        wd[t + 1536] = wsv[t + 1536];
    }
    if (t < 64) { bsh[t] = bias[t]; cnt[t] = 0; }
    if (t == 0) mtot = 0;
    __syncthreads();

    const int b   = (int)blockIdx.x;
    const int nlo = b << KB_SHIFT;

    // A': collect this bucket's segment from every tile (reads, no global RMW)
    for (int tl = t; tl < n_stiles; tl += 512) {
        const unsigned short* ob = offs + (size_t)tl * (K + 1) + b;
        int s0 = (int)ob[0], e0 = (int)ob[1];
        int len = e0 - s0;
        if (len > 0) {
            int pos = atomicAdd(&mtot, len);
            const unsigned* pp = pairs + (size_t)tl * STILE + s0;
            for (int i = 0; i < len; ++i) {
                int p2 = pos + i;
                if (p2 < CAP) list_raw[p2] = pp[i];
            }
        }
    }
    __syncthreads();
    int m = mtot; if (m > CAP) m = CAP;

    // A: single-atomic-pass local CSR
    unsigned lp[4]; int lr[4];
    #pragma unroll
    for (int i = 0; i < 4; ++i) {
        int idx = t + i * 512;
        lr[i] = -1;
        if (idx < m) {
            lp[i] = list_raw[idx];
            lr[i] = atomicAdd(&cnt[lp[i] & (BKN - 1)], 1);
        }
    }
    __syncthreads();
    if (t < 64) {            // wave 0 scans the 64 counters
        int v = cnt[t];
        int incl = v;
        #pragma unroll
        for (int off = 1; off < 64; off <<= 1) {
            int x = __shfl_up(incl, off);
            if (t >= off) incl += x;
        }
        rs[t] = incl - v;
        if (t == 63) rs[64] = incl;
    }
    __syncthreads();
    #pragma unroll
    for (int i = 0; i < 4; ++i)
        if (lr[i] >= 0)
            list[rs[lp[i] & (BKN - 1)] + lr[i]] = (int)(lp[i] >> KB_SHIFT);
    __syncthreads();     // list_raw dead from here; hn reuses its LDS

    const int w    = t >> 6;
    const int lane = t & 63;
    const int sub  = lane >> 4;
    const int q    = lane & 15;

    // B: gather — wave w owns nodes w*8..w*8+7
    for (int i = 0; i < 8; ++i) {
        int nl = w * 8 + i;
        int n  = nlo + nl;
        if (n >= n_nodes) break;               // wave-uniform
        int beg = rs[nl], end = rs[nl + 1];
        float4 acc = make_float4(0.f, 0.f, 0.f, 0.f);
        int e = beg + sub;
        for (; e + 12 < end; e += 16) {        // 4 edges in flight per lane
            int s0 = list[e], s1 = list[e + 4], s2 = list[e + 8], s3 = list[e + 12];
            const ushort4 u0 = *(const ushort4*)(hb + ((size_t)s0 << 6) + q * 4);
            const ushort4 u1 = *(const ushort4*)(hb + ((size_t)s1 << 6) + q * 4);
            const ushort4 u2 = *(const ushort4*)(hb + ((size_t)s2 << 6) + q * 4);
            const ushort4 u3 = *(const ushort4*)(hb + ((size_t)s3 << 6) + q * 4);
            acc.x += (bf2f(u0.x) + bf2f(u1.x)) + (bf2f(u2.x) + bf2f(u3.x));
            acc.y += (bf2f(u0.y) + bf2f(u1.y)) + (bf2f(u2.y) + bf2f(u3.y));
            acc.z += (bf2f(u0.z) + bf2f(u1.z)) + (bf2f(u2.z) + bf2f(u3.z));
            acc.w += (bf2f(u0.w) + bf2f(u1.w)) + (bf2f(u2.w) + bf2f(u3.w));
        }
        for (; e + 4 < end; e += 8) {
            int s0 = list[e], s1 = list[e + 4];
            const ushort4 u0 = *(const ushort4*)(hb + ((size_t)s0 << 6) + q * 4);
            const ushort4 u1 = *(const ushort4*)(hb + ((size_t)s1 << 6) + q * 4);
            acc.x += bf2f(u0.x) + bf2f(u1.x);
            acc.y += bf2f(u0.y) + bf2f(u1.y);
            acc.z += bf2f(u0.z) + bf2f(u1.z);
            acc.w += bf2f(u0.w) + bf2f(u1.w);
        }
        if (e < end) {
            int s0 = list[e];
            const ushort4 u0 = *(const ushort4*)(hb + ((size_t)s0 << 6) + q * 4);
            acc.x += bf2f(u0.x); acc.y += bf2f(u0.y);
            acc.z += bf2f(u0.z); acc.w += bf2f(u0.w);
        }
        #pragma unroll
        for (int mm = 16; mm < 64; mm <<= 1) {
            acc.x += __shfl_xor(acc.x, mm);
            acc.y += __shfl_xor(acc.y, mm);
            acc.z += __shfl_xor(acc.z, mm);
            acc.w += __shfl_xor(acc.w, mm);
        }
        int deg = end - beg;
        float inv = (deg > 0) ? (1.0f / (float)deg) : 0.f;
        if (sub == 0) {
            ushort4 r;
            r.x = f2bf(acc.x * inv); r.y = f2bf(acc.y * inv);
            r.z = f2bf(acc.z * inv); r.w = f2bf(acc.w * inv);
            *(ushort4*)&hn[nl][q * 4] = r;
        }
    }
    __builtin_amdgcn_wave_barrier();   // hn is wave-private; scheduling fence

    // C: MLP — wave w, pass p: node w*8 + p*4 + sub
    #pragma unroll
    for (int p = 0; p < 2; ++p) {
        int nl = w * 8 + p * 4 + sub;
        int n  = nlo + nl;
        if (n < n_nodes) {
            const float* hrow = h + ((size_t)n << 6);
            float4 o = ((const float4*)bsh)[q];
            #pragma unroll
            for (int k4 = 0; k4 < 16; ++k4) {
                const float4 hq = *(const float4*)(hrow + k4 * 4);   // bcast x16
                #pragma unroll
                for (int c = 0; c < 4; ++c) {
                    float hv = (&hq.x)[c];
                    const float4 wv = *(const float4*)&Wsh[k4 * 4 + c][q * 4];
                    o.x = fmaf(hv, wv.x, o.x);
                    o.y = fmaf(hv, wv.y, o.y);
                    o.z = fmaf(hv, wv.z, o.z);
                    o.w = fmaf(hv, wv.w, o.w);
                }
            }
            #pragma unroll 16
            for (int k = 0; k < 64; ++k) {
                float hv = bf2f(hn[nl][k]);
                const float4 wv = *(const float4*)&Wsh[64 + k][q * 4];
                o.x = fmaf(hv, wv.x, o.x);
                o.y = fmaf(hv, wv.y, o.y);
                o.z = fmaf(hv, wv.z, o.z);
                o.w = fmaf(hv, wv.w, o.w);
            }
            *(float4*)(out + ((size_t)n << 6) + q * 4) = o;
        }
    }
}

extern "C" void kernel_launch(void* const* d_in, const int* in_sizes, int n_in,
                              void* d_out, int out_size, void* d_ws, size_t ws_size,
                              hipStream_t stream) {
    const float* h   = (const float*)d_in[0];
    const int*   src = (const int*)d_in[1];
    const int*   dst = (const int*)d_in[2];
    const float* W   = (const float*)d_in[3];
    const float* b   = (const float*)d_in[4];
    float* out = (float*)d_out;

    const int n_nodes = in_sizes[0] / IN_FEAT;
    const int n_edges = in_sizes[1];
    const int K  = (n_nodes + BKN - 1) >> KB_SHIFT;    // 782
    const int n4 = n_nodes * (IN_FEAT / 4);            // 800000 float4s

    const int conv_tiles = (n4 + 8191) / 8192;         // 98
    const int n_stiles   = (n_edges + STILE - 1) / STILE;  // 196

    // ws: hb[N*64 ushort] | pairs[n_stiles*STILE u32] | offs[n_stiles*(K+1) ushort]
    unsigned short* hb   = (unsigned short*)d_ws;
    unsigned* pairs      = (unsigned*)(hb + (size_t)n_nodes * IN_FEAT);
    unsigned short* offs = (unsigned short*)(pairs + (size_t)n_stiles * STILE);

    sage_prep<<<conv_tiles + n_stiles, 512, 0, stream>>>(
        h, src, dst, hb, pairs, offs, n4, n_edges, conv_tiles, K);
    sage_fused<<<K, 512, 0, stream>>>(hb, h, pairs, offs, W, b, out,
                                      n_nodes, K, n_stiles);
}